// Round 13
// baseline (1905.988 us; speedup 1.0000x reference)
//
#include <hip/hip_runtime.h>

#define N_NODES 10000
#define N_EDGES 320000
#define N_CAND  100000
#define HID     256
#define N_MP    3
#define N_ATYPE 100

#define MG_BLOCKS  1024
#define MG_THREADS 256
#define MG_NT      (MG_BLOCKS * MG_THREADS)   // 262144 threads
#define MG_NW      (MG_NT / 64)               // 4096 waves
#define NPB        10                         // nodes per block (scan phases)

typedef short bf16x8 __attribute__((ext_vector_type(8)));
typedef float f32x4  __attribute__((ext_vector_type(4)));

static __device__ __forceinline__ float relu_f(float x) { return x > 0.f ? x : 0.f; }

// split fp32 -> bf16 hi (truncate) + bf16 lo (RNE of residual)
static __device__ __forceinline__ void split_bf16(float s, unsigned short& hi,
                                                  unsigned short& lo)
{
    unsigned u = __float_as_uint(s);
    hi = (unsigned short)(u >> 16);
    float rem = s - __uint_as_float(u & 0xffff0000u);
    unsigned v = __float_as_uint(rem);
    unsigned r = v + 0x7fffu + ((v >> 16) & 1u);
    lo = (unsigned short)(r >> 16);
}

// ---------------------------------------------------------------------------
// Software grid barrier, contention-fixed: arrival = ONE agent-scope RMW;
// wait = agent-scope atomic LOADS (no RMW -> no serialization storm).
// Counters zeroed by the captured memsetAsync each launch; each counter is
// passed exactly once per launch, so target is simply MG_BLOCKS.
// Residency: launch_bounds(256,4) => VGPR<=128 => >=4 blocks/CU => capacity
// >= 1024 = grid (measured VGPR=64 in R12 => real capacity 2048, 2x margin).
// ---------------------------------------------------------------------------
static __device__ __forceinline__ void gsync(unsigned* ctr)
{
    __syncthreads();
    if (threadIdx.x == 0) {
        __threadfence();
        __hip_atomic_fetch_add(ctr, 1u, __ATOMIC_RELAXED, __HIP_MEMORY_SCOPE_AGENT);
        while (__hip_atomic_load(ctr, __ATOMIC_RELAXED, __HIP_MEMORY_SCOPE_AGENT)
               < (unsigned)MG_BLOCKS)
            __builtin_amdgcn_s_sleep(4);
        __threadfence();
    }
    __syncthreads();
}

// ---------------------------------------------------------------------------
// bf16x3 MFMA 32x32 tile (verified R10/R12: absmax 3.8e-6).
// outF != null -> fp32 store; else split-bf16 store to outH/outL.
// ---------------------------------------------------------------------------
static __device__ __forceinline__ void mfma_tile(
    const unsigned short* __restrict__ Ah, const unsigned short* __restrict__ Al,
    const unsigned short* __restrict__ Wh, const unsigned short* __restrict__ Wl,
    const float* __restrict__ bias, const float* __restrict__ scale,
    float* __restrict__ outF, unsigned short* __restrict__ outH,
    unsigned short* __restrict__ outL,
    int M, int mb, int nb, int doRelu)
{
    int l  = threadIdx.x & 63;
    int li = l & 15;
    int g  = l >> 4;

    int r0 = mb + li;       if (r0 >= M) r0 = M - 1;
    int r1 = mb + 16 + li;  if (r1 >= M) r1 = M - 1;
    int c0 = nb + li;
    int c1 = nb + 16 + li;

    const unsigned short* pA0h = Ah + (size_t)r0 * 256 + g * 8;
    const unsigned short* pA1h = Ah + (size_t)r1 * 256 + g * 8;
    const unsigned short* pA0l = Al + (size_t)r0 * 256 + g * 8;
    const unsigned short* pA1l = Al + (size_t)r1 * 256 + g * 8;
    const unsigned short* pB0h = Wh + (size_t)c0 * 256 + g * 8;
    const unsigned short* pB1h = Wh + (size_t)c1 * 256 + g * 8;
    const unsigned short* pB0l = Wl + (size_t)c0 * 256 + g * 8;
    const unsigned short* pB1l = Wl + (size_t)c1 * 256 + g * 8;

    f32x4 acc00 = {0.f, 0.f, 0.f, 0.f};
    f32x4 acc01 = {0.f, 0.f, 0.f, 0.f};
    f32x4 acc10 = {0.f, 0.f, 0.f, 0.f};
    f32x4 acc11 = {0.f, 0.f, 0.f, 0.f};

    #pragma unroll
    for (int ks = 0; ks < 8; ++ks) {
        int o = ks * 32;
        bf16x8 a0h = *(const bf16x8*)(pA0h + o);
        bf16x8 a1h = *(const bf16x8*)(pA1h + o);
        bf16x8 a0l = *(const bf16x8*)(pA0l + o);
        bf16x8 a1l = *(const bf16x8*)(pA1l + o);
        bf16x8 b0h = *(const bf16x8*)(pB0h + o);
        bf16x8 b1h = *(const bf16x8*)(pB1h + o);
        bf16x8 b0l = *(const bf16x8*)(pB0l + o);
        bf16x8 b1l = *(const bf16x8*)(pB1l + o);

        acc00 = __builtin_amdgcn_mfma_f32_16x16x32_bf16(a0h, b0h, acc00, 0, 0, 0);
        acc01 = __builtin_amdgcn_mfma_f32_16x16x32_bf16(a0h, b1h, acc01, 0, 0, 0);
        acc10 = __builtin_amdgcn_mfma_f32_16x16x32_bf16(a1h, b0h, acc10, 0, 0, 0);
        acc11 = __builtin_amdgcn_mfma_f32_16x16x32_bf16(a1h, b1h, acc11, 0, 0, 0);

        acc00 = __builtin_amdgcn_mfma_f32_16x16x32_bf16(a0h, b0l, acc00, 0, 0, 0);
        acc01 = __builtin_amdgcn_mfma_f32_16x16x32_bf16(a0h, b1l, acc01, 0, 0, 0);
        acc10 = __builtin_amdgcn_mfma_f32_16x16x32_bf16(a1h, b0l, acc10, 0, 0, 0);
        acc11 = __builtin_amdgcn_mfma_f32_16x16x32_bf16(a1h, b1l, acc11, 0, 0, 0);

        acc00 = __builtin_amdgcn_mfma_f32_16x16x32_bf16(a0l, b0h, acc00, 0, 0, 0);
        acc01 = __builtin_amdgcn_mfma_f32_16x16x32_bf16(a0l, b1h, acc01, 0, 0, 0);
        acc10 = __builtin_amdgcn_mfma_f32_16x16x32_bf16(a1l, b0h, acc10, 0, 0, 0);
        acc11 = __builtin_amdgcn_mfma_f32_16x16x32_bf16(a1l, b1h, acc11, 0, 0, 0);
    }

    #pragma unroll
    for (int rt = 0; rt < 2; ++rt) {
        #pragma unroll
        for (int ct = 0; ct < 2; ++ct) {
            f32x4 a = rt ? (ct ? acc11 : acc10) : (ct ? acc01 : acc00);
            int col = nb + ct * 16 + li;
            float bv = bias ? bias[col] : 0.f;
            #pragma unroll
            for (int j = 0; j < 4; ++j) {
                int row = mb + rt * 16 + g * 4 + j;
                if (row >= M) continue;
                float v = a[j] + bv;
                if (doRelu) v = relu_f(v);
                if (scale) v *= scale[row];
                if (outF) {
                    outF[(size_t)row * 256 + col] = v;
                } else {
                    unsigned short hi, lo;
                    split_bf16(v, hi, lo);
                    outH[(size_t)row * 256 + col] = hi;
                    outL[(size_t)row * 256 + col] = lo;
                }
            }
        }
    }
}

// ===========================================================================
struct MegaParams {
    const int*   atom_types;
    const int*   edge_index;
    const int*   candidates;
    const float* atom_embed;
    const float* atom_W;
    const float* atom_b;
    const float* conv_W;
    const float* conv_b;
    const float* s_W1;
    const float* s_b1;
    const float* s_W2;
    const float* s_b2;
    float* E0; float* h0; float* h1; float* Pm; float* Qm;
    float* ns; float* nd; float* part; float* out;
    unsigned short* Ah; unsigned short* Al;
    unsigned short* Ah2; unsigned short* Al2;
    unsigned short* WTh; unsigned short* WTl;
    int* dego; int* degi; int* cur; int* off; int* csr;
    int* bsum; int* bpre;
    unsigned* bar;
};

__global__ __launch_bounds__(MG_THREADS, 4) void k_mega(MegaParams P)
{
    const int tid  = blockIdx.x * MG_THREADS + threadIdx.x;
    const int wid  = tid >> 6;
    const int lane = threadIdx.x & 63;
    __shared__ int sh[256];
    unsigned* B = P.bar;

    // ---- P0: weight prep (split+transpose) + E0 GEMM (wave-parallel) +
    //          degree histogram. All independent; ints zeroed by host memset.
    for (int idx = tid; idx < 5 * 65536; idx += MG_NT) {
        int mat = idx >> 16;
        int e   = idx & 65535;
        int n   = e >> 8;
        int k   = e & 255;
        const float* src = (mat < 3) ? P.conv_W + (size_t)mat * 65536
                                     : P.s_W1 + (size_t)(mat - 3) * 65536;
        unsigned short hi, lo;
        split_bf16(src[(size_t)k * 256 + n], hi, lo);
        size_t oi = (size_t)mat * 65536 + (size_t)n * 256 + k;
        P.WTh[oi] = hi;
        P.WTl[oi] = lo;
    }
    if (wid < N_ATYPE) {            // E0 row per wave: lane owns 4 cols
        int r = wid;
        float4 acc = ((const float4*)P.atom_b)[lane];
        for (int k = 0; k < 256; ++k) {
            float a = P.atom_embed[(size_t)r * 256 + k];
            float4 w4 = ((const float4*)P.atom_W)[(size_t)k * 64 + lane];
            acc.x = fmaf(a, w4.x, acc.x);
            acc.y = fmaf(a, w4.y, acc.y);
            acc.z = fmaf(a, w4.z, acc.z);
            acc.w = fmaf(a, w4.w, acc.w);
        }
        ((float4*)P.E0)[(size_t)r * 64 + lane] = acc;
    }
    for (int e = tid; e < N_EDGES; e += MG_NT) {
        atomicAdd(&P.dego[P.edge_index[e]], 1);
        atomicAdd(&P.degi[P.edge_index[N_EDGES + e]], 1);
    }
    gsync(B + 0);

    // ---- P2: norms + h0 (pre-scaled by ns) + per-block degi partial sums ----
    for (int node = wid; node < N_NODES; node += MG_NW) {
        int o  = P.dego[node];
        int in = P.degi[node];
        float nsv = (o  > 0) ? (1.0f / sqrtf((float)o))  : 0.f;
        float ndv = (in > 0) ? (1.0f / sqrtf((float)in)) : 0.f;
        if (lane == 0) { P.ns[node] = nsv; P.nd[node] = ndv; }
        int t = P.atom_types[node];
        float4 v = ((const float4*)P.E0)[(size_t)t * 64 + lane];
        v.x *= nsv; v.y *= nsv; v.z *= nsv; v.w *= nsv;
        ((float4*)P.h0)[(size_t)node * 64 + lane] = v;
    }
    if (threadIdx.x == 0) {
        int b = blockIdx.x, s = 0;
        for (int i = 0; i < NPB; ++i) {
            int j = b * NPB + i;
            if (j < N_NODES) s += P.degi[j];
        }
        P.bsum[b] = s;
    }
    gsync(B + 1);

    // ---- P3: block 0 scans bsum[1024] -> bpre (exclusive) ----
    if (blockIdx.x == 0) {
        int t = threadIdx.x;
        int v0 = P.bsum[4 * t],     v1 = P.bsum[4 * t + 1];
        int v2 = P.bsum[4 * t + 2], v3 = P.bsum[4 * t + 3];
        sh[t] = v0 + v1 + v2 + v3;
        __syncthreads();
        for (int d = 1; d < 256; d <<= 1) {
            int v = (t >= d) ? sh[t - d] : 0;
            __syncthreads();
            sh[t] += v;
            __syncthreads();
        }
        int base = (t > 0) ? sh[t - 1] : 0;
        P.bpre[4 * t]     = base;
        P.bpre[4 * t + 1] = base + v0;
        P.bpre[4 * t + 2] = base + v0 + v1;
        P.bpre[4 * t + 3] = base + v0 + v1 + v2;
    }
    gsync(B + 2);

    // ---- P4: write CSR row offsets ----
    if (threadIdx.x == 0) {
        int b = blockIdx.x;
        int run = P.bpre[b];
        for (int i = 0; i < NPB; ++i) {
            int j = b * NPB + i;
            if (j < N_NODES) { P.off[j] = run; run += P.degi[j]; }
        }
        if (b == MG_BLOCKS - 1) P.off[N_NODES] = run;
    }
    gsync(B + 3);

    // ---- P5: CSR fill ----
    for (int e = tid; e < N_EDGES; e += MG_NT) {
        int d = P.edge_index[N_EDGES + e];
        int p = P.off[d] + atomicAdd(&P.cur[d], 1);
        P.csr[p] = P.edge_index[e];
    }
    gsync(B + 4);

    // ---- message-passing layers: (agg -> conv) x 3 ----
    const float* hc = P.h0;
    float* hn = P.h1;
    int bi = 5;
    for (int L = 0; L < N_MP; ++L) {
        // agg: column-chunked (chunk pinned to XCD pair), unroll-8, split-bf16 out
        {
            int slot = blockIdx.x & 7;
            int c    = slot >> 1;
            int p2   = ((blockIdx.x >> 3) << 1) | (slot & 1);   // 0..255
            int wv   = threadIdx.x >> 6;
            int wi   = p2 * 4 + wv;                              // 0..1023
            int col  = c * 64 + lane;
            for (int node = wi; node < N_NODES; node += 1024) {
                int s0 = P.off[node], s1 = P.off[node + 1];
                float a0 = 0.f, a1 = 0.f, a2 = 0.f, a3 = 0.f;
                float a4 = 0.f, a5 = 0.f, a6 = 0.f, a7 = 0.f;
                int e = s0;
                for (; e + 8 <= s1; e += 8) {
                    int i0 = P.csr[e],     i1 = P.csr[e + 1];
                    int i2 = P.csr[e + 2], i3 = P.csr[e + 3];
                    int i4 = P.csr[e + 4], i5 = P.csr[e + 5];
                    int i6 = P.csr[e + 6], i7 = P.csr[e + 7];
                    float v0 = hc[(size_t)i0 * 256 + col];
                    float v1 = hc[(size_t)i1 * 256 + col];
                    float v2 = hc[(size_t)i2 * 256 + col];
                    float v3 = hc[(size_t)i3 * 256 + col];
                    float v4 = hc[(size_t)i4 * 256 + col];
                    float v5 = hc[(size_t)i5 * 256 + col];
                    float v6 = hc[(size_t)i6 * 256 + col];
                    float v7 = hc[(size_t)i7 * 256 + col];
                    a0 += v0; a1 += v1; a2 += v2; a3 += v3;
                    a4 += v4; a5 += v5; a6 += v6; a7 += v7;
                }
                for (; e < s1; ++e)
                    a0 += hc[(size_t)P.csr[e] * 256 + col];
                float s = (((a0 + a1) + (a2 + a3)) + ((a4 + a5) + (a6 + a7)))
                          * P.nd[node];
                unsigned short hi, lo;
                split_bf16(s, hi, lo);
                P.Ah[(size_t)node * 256 + col] = hi;
                P.Al[(size_t)node * 256 + col] = lo;
            }
        }
        gsync(B + bi); ++bi;
        // conv: MFMA 32x32 wave-tiles; last layer stores split-bf16 for pq
        {
            const unsigned short* Wh = P.WTh + (size_t)L * 65536;
            const unsigned short* Wl = P.WTl + (size_t)L * 65536;
            const float* bias = P.conv_b + (size_t)L * 256;
            const float* sc   = (L < N_MP - 1) ? P.ns : nullptr;
            float* outF = (L < N_MP - 1) ? hn : nullptr;
            for (int t = wid; t < 313 * 8; t += MG_NW) {
                int x = t >> 3, y = t & 7;
                mfma_tile(P.Ah, P.Al, Wh, Wl, bias, sc,
                          outF, P.Ah2, P.Al2, N_NODES, x * 32, y * 32, 1);
            }
        }
        gsync(B + bi); ++bi;
        const float* tswap = hc; hc = hn; hn = (float*)tswap;
    }

    // ---- P12: P/Q projection (reads Ah2/Al2 from last conv) ----
    for (int t = wid; t < 313 * 16; t += MG_NW) {
        int x = t >> 4, r = t & 15;
        int half = r >> 3, y = r & 7;
        const unsigned short* wh = P.WTh + (size_t)(3 + half) * 65536;
        const unsigned short* wl = P.WTl + (size_t)(3 + half) * 65536;
        mfma_tile(P.Ah2, P.Al2, wh, wl, nullptr, nullptr,
                  half ? P.Qm : P.Pm, nullptr, nullptr, N_NODES, x * 32, y * 32, 0);
    }
    gsync(B + 11);

    // ---- P13: scoring, 8 col-chunks pinned to XCDs ----
    {
        int c  = blockIdx.x & 7;
        int bc = blockIdx.x >> 3;                    // 0..127
        const float4* P4 = (const float4*)P.Pm;
        const float4* Q4 = (const float4*)P.Qm;
        const float4* B4 = (const float4*)P.s_b1;
        const float4* W4 = (const float4*)P.s_W2;
        for (int cd = bc * 256 + threadIdx.x; cd < N_CAND; cd += 128 * 256) {
            int u = P.candidates[2 * cd];
            int v = P.candidates[2 * cd + 1];
            size_t pb = (size_t)u * 64 + c * 8;
            size_t qb = (size_t)v * 64 + c * 8;
            float4 p[8], q[8];
            #pragma unroll
            for (int i = 0; i < 8; ++i) p[i] = P4[pb + i];
            #pragma unroll
            for (int i = 0; i < 8; ++i) q[i] = Q4[qb + i];
            float acc = 0.f;
            #pragma unroll
            for (int i = 0; i < 8; ++i) {
                float4 b = B4[c * 8 + i];
                float4 w = W4[c * 8 + i];
                acc = fmaf(relu_f(p[i].x + q[i].x + b.x), w.x, acc);
                acc = fmaf(relu_f(p[i].y + q[i].y + b.y), w.y, acc);
                acc = fmaf(relu_f(p[i].z + q[i].z + b.z), w.z, acc);
                acc = fmaf(relu_f(p[i].w + q[i].w + b.w), w.w, acc);
            }
            P.part[(size_t)c * N_CAND + cd] = acc;
        }
    }
    gsync(B + 12);

    // ---- P14: reduce partials ----
    for (int i = tid; i < N_CAND; i += MG_NT) {
        float s = P.s_b2[0];
        #pragma unroll
        for (int c = 0; c < 8; ++c) s += P.part[(size_t)c * N_CAND + i];
        P.out[i] = s;
    }
}

// ---------------------------------------------------------------------------
extern "C" void kernel_launch(void* const* d_in, const int* in_sizes, int n_in,
                              void* d_out, int out_size, void* d_ws, size_t ws_size,
                              hipStream_t stream)
{
    const int*   atom_types = (const int*)d_in[0];
    const int*   edge_index = (const int*)d_in[2];
    const int*   candidates = (const int*)d_in[3];
    const float* atom_embed = (const float*)d_in[4];
    const float* atom_W     = (const float*)d_in[5];
    const float* atom_b     = (const float*)d_in[6];
    const float* conv_W     = (const float*)d_in[10];
    const float* conv_b     = (const float*)d_in[11];
    const float* s_W1       = (const float*)d_in[12];
    const float* s_b1       = (const float*)d_in[13];
    const float* s_W2       = (const float*)d_in[14];
    const float* s_b2       = (const float*)d_in[15];
    float* out = (float*)d_out;

    char* w = (char*)d_ws;
    size_t o = 0;
    auto alloc = [&](size_t bytes) {
        void* p = w + o;
        o += (bytes + 255) & ~(size_t)255;
        return p;
    };
    // bar + ints first and contiguous so ONE memset zeroes both
    unsigned*       bar  = (unsigned*)alloc((size_t)64 * 4);         // 256 B
    int*            ints = (int*)alloc((size_t)3 * N_NODES * 4);     // dego|degi|cur
    float*          h0   = (float*)alloc((size_t)N_NODES * HID * 4);
    float*          h1   = (float*)alloc((size_t)N_NODES * HID * 4);
    float*          Pm   = (float*)alloc((size_t)N_NODES * HID * 4);
    float*          Qm   = (float*)alloc((size_t)N_NODES * HID * 4);
    unsigned short* Ah   = (unsigned short*)alloc((size_t)N_NODES * HID * 2);
    unsigned short* Al   = (unsigned short*)alloc((size_t)N_NODES * HID * 2);
    unsigned short* Ah2  = (unsigned short*)alloc((size_t)N_NODES * HID * 2);
    unsigned short* Al2  = (unsigned short*)alloc((size_t)N_NODES * HID * 2);
    unsigned short* WTh  = (unsigned short*)alloc((size_t)5 * 65536 * 2);
    unsigned short* WTl  = (unsigned short*)alloc((size_t)5 * 65536 * 2);
    float*          E0   = (float*)alloc((size_t)N_ATYPE * HID * 4);
    float*          part = (float*)alloc((size_t)8 * N_CAND * 4);
    float*          ns   = (float*)alloc((size_t)N_NODES * 4);
    float*          nd   = (float*)alloc((size_t)N_NODES * 4);
    int*            off  = (int*)alloc((size_t)(N_NODES + 1) * 4);
    int*            csr  = (int*)alloc((size_t)N_EDGES * 4);
    int*            bsum = (int*)alloc((size_t)MG_BLOCKS * 4);
    int*            bpre = (int*)alloc((size_t)MG_BLOCKS * 4);

    // zero barrier counters + degree/cursor arrays (graph-replayed each call)
    hipMemsetAsync(bar, 0, 256 + (size_t)3 * N_NODES * 4, stream);

    MegaParams mp;
    mp.atom_types = atom_types; mp.edge_index = edge_index;
    mp.candidates = candidates; mp.atom_embed = atom_embed;
    mp.atom_W = atom_W; mp.atom_b = atom_b;
    mp.conv_W = conv_W; mp.conv_b = conv_b;
    mp.s_W1 = s_W1; mp.s_b1 = s_b1; mp.s_W2 = s_W2; mp.s_b2 = s_b2;
    mp.E0 = E0; mp.h0 = h0; mp.h1 = h1; mp.Pm = Pm; mp.Qm = Qm;
    mp.ns = ns; mp.nd = nd; mp.part = part; mp.out = out;
    mp.Ah = Ah; mp.Al = Al; mp.Ah2 = Ah2; mp.Al2 = Al2;
    mp.WTh = WTh; mp.WTl = WTl;
    mp.dego = ints; mp.degi = ints + N_NODES; mp.cur = ints + 2 * N_NODES;
    mp.off = off; mp.csr = csr; mp.bsum = bsum; mp.bpre = bpre;
    mp.bar = bar;

    k_mega<<<MG_BLOCKS, MG_THREADS, 0, stream>>>(mp);
}

// Round 14
// 337.151 us; speedup vs baseline: 5.6532x; 5.6532x over previous
//
#include <hip/hip_runtime.h>

#define N_NODES 10000
#define N_EDGES 320000
#define N_CAND  100000
#define HID     256
#define N_MP    3
#define N_ATYPE 100

typedef short bf16x8 __attribute__((ext_vector_type(8)));
typedef float f32x4  __attribute__((ext_vector_type(4)));

static __device__ __forceinline__ float relu_f(float x) { return x > 0.f ? x : 0.f; }

// split fp32 -> bf16 hi (truncate) + bf16 lo (RNE of residual)
static __device__ __forceinline__ void split_bf16(float s, unsigned short& hi,
                                                  unsigned short& lo)
{
    unsigned u = __float_as_uint(s);
    hi = (unsigned short)(u >> 16);
    float rem = s - __uint_as_float(u & 0xffff0000u);
    unsigned v = __float_as_uint(rem);
    unsigned r = v + 0x7fffu + ((v >> 16) & 1u);
    lo = (unsigned short)(r >> 16);
}

// ---------------------------------------------------------------------------
// bf16x3 MFMA 32x32 tile (verified R10/R12/R13: absmax 3.8e-6).
// outF != null -> fp32 store; else split-bf16 store to outH/outL.
// ---------------------------------------------------------------------------
static __device__ __forceinline__ void mfma_tile(
    const unsigned short* __restrict__ Ah, const unsigned short* __restrict__ Al,
    const unsigned short* __restrict__ Wh, const unsigned short* __restrict__ Wl,
    const float* __restrict__ bias, const float* __restrict__ scale,
    float* __restrict__ outF, unsigned short* __restrict__ outH,
    unsigned short* __restrict__ outL,
    int M, int mb, int nb, int doRelu)
{
    int l  = threadIdx.x & 63;
    int li = l & 15;
    int g  = l >> 4;

    int r0 = mb + li;       if (r0 >= M) r0 = M - 1;
    int r1 = mb + 16 + li;  if (r1 >= M) r1 = M - 1;
    int c0 = nb + li;
    int c1 = nb + 16 + li;

    const unsigned short* pA0h = Ah + (size_t)r0 * 256 + g * 8;
    const unsigned short* pA1h = Ah + (size_t)r1 * 256 + g * 8;
    const unsigned short* pA0l = Al + (size_t)r0 * 256 + g * 8;
    const unsigned short* pA1l = Al + (size_t)r1 * 256 + g * 8;
    const unsigned short* pB0h = Wh + (size_t)c0 * 256 + g * 8;
    const unsigned short* pB1h = Wh + (size_t)c1 * 256 + g * 8;
    const unsigned short* pB0l = Wl + (size_t)c0 * 256 + g * 8;
    const unsigned short* pB1l = Wl + (size_t)c1 * 256 + g * 8;

    f32x4 acc00 = {0.f, 0.f, 0.f, 0.f};
    f32x4 acc01 = {0.f, 0.f, 0.f, 0.f};
    f32x4 acc10 = {0.f, 0.f, 0.f, 0.f};
    f32x4 acc11 = {0.f, 0.f, 0.f, 0.f};

    #pragma unroll
    for (int ks = 0; ks < 8; ++ks) {
        int o = ks * 32;
        bf16x8 a0h = *(const bf16x8*)(pA0h + o);
        bf16x8 a1h = *(const bf16x8*)(pA1h + o);
        bf16x8 a0l = *(const bf16x8*)(pA0l + o);
        bf16x8 a1l = *(const bf16x8*)(pA1l + o);
        bf16x8 b0h = *(const bf16x8*)(pB0h + o);
        bf16x8 b1h = *(const bf16x8*)(pB1h + o);
        bf16x8 b0l = *(const bf16x8*)(pB0l + o);
        bf16x8 b1l = *(const bf16x8*)(pB1l + o);

        acc00 = __builtin_amdgcn_mfma_f32_16x16x32_bf16(a0h, b0h, acc00, 0, 0, 0);
        acc01 = __builtin_amdgcn_mfma_f32_16x16x32_bf16(a0h, b1h, acc01, 0, 0, 0);
        acc10 = __builtin_amdgcn_mfma_f32_16x16x32_bf16(a1h, b0h, acc10, 0, 0, 0);
        acc11 = __builtin_amdgcn_mfma_f32_16x16x32_bf16(a1h, b1h, acc11, 0, 0, 0);

        acc00 = __builtin_amdgcn_mfma_f32_16x16x32_bf16(a0h, b0l, acc00, 0, 0, 0);
        acc01 = __builtin_amdgcn_mfma_f32_16x16x32_bf16(a0h, b1l, acc01, 0, 0, 0);
        acc10 = __builtin_amdgcn_mfma_f32_16x16x32_bf16(a1h, b0l, acc10, 0, 0, 0);
        acc11 = __builtin_amdgcn_mfma_f32_16x16x32_bf16(a1h, b1l, acc11, 0, 0, 0);

        acc00 = __builtin_amdgcn_mfma_f32_16x16x32_bf16(a0l, b0h, acc00, 0, 0, 0);
        acc01 = __builtin_amdgcn_mfma_f32_16x16x32_bf16(a0l, b1h, acc01, 0, 0, 0);
        acc10 = __builtin_amdgcn_mfma_f32_16x16x32_bf16(a1l, b0h, acc10, 0, 0, 0);
        acc11 = __builtin_amdgcn_mfma_f32_16x16x32_bf16(a1l, b1h, acc11, 0, 0, 0);
    }

    #pragma unroll
    for (int rt = 0; rt < 2; ++rt) {
        #pragma unroll
        for (int ct = 0; ct < 2; ++ct) {
            f32x4 a = rt ? (ct ? acc11 : acc10) : (ct ? acc01 : acc00);
            int col = nb + ct * 16 + li;
            float bv = bias ? bias[col] : 0.f;
            #pragma unroll
            for (int j = 0; j < 4; ++j) {
                int row = mb + rt * 16 + g * 4 + j;
                if (row >= M) continue;
                float v = a[j] + bv;
                if (doRelu) v = relu_f(v);
                if (scale) v *= scale[row];
                if (outF) {
                    outF[(size_t)row * 256 + col] = v;
                } else {
                    unsigned short hi, lo;
                    split_bf16(v, hi, lo);
                    outH[(size_t)row * 256 + col] = hi;
                    outL[(size_t)row * 256 + col] = lo;
                }
            }
        }
    }
}

// ---------------------------------------------------------------------------
// k_pre: prep_w (split+transpose, all 5 mats) + E0 GEMM (wave-parallel) +
// degree histogram. All mutually independent. Grid: 1280 x 256.
// ---------------------------------------------------------------------------
__global__ __launch_bounds__(256) void k_pre(
    const float* __restrict__ conv_W, const float* __restrict__ s_W1,
    const float* __restrict__ atom_embed, const float* __restrict__ atom_W,
    const float* __restrict__ atom_b, const int* __restrict__ ei,
    unsigned short* __restrict__ WTh, unsigned short* __restrict__ WTl,
    float* __restrict__ E0, int* __restrict__ dout, int* __restrict__ din)
{
    int gidx = blockIdx.x * 256 + threadIdx.x;   // 0..327679
    // weight prep (exactly covers 5*65536)
    {
        int mat = gidx >> 16;
        int e   = gidx & 65535;
        int n   = e >> 8;
        int k   = e & 255;
        const float* src = (mat < 3) ? conv_W + (size_t)mat * 65536
                                     : s_W1 + (size_t)(mat - 3) * 65536;
        unsigned short hi, lo;
        split_bf16(src[(size_t)k * 256 + n], hi, lo);
        size_t oi = (size_t)mat * 65536 + (size_t)n * 256 + k;
        WTh[oi] = hi;
        WTl[oi] = lo;
    }
    // E0: wave r computes row r (lane owns 4 cols)  [verified R13 P0]
    int wid  = gidx >> 6;
    int lane = threadIdx.x & 63;
    if (wid < N_ATYPE) {
        int r = wid;
        float4 acc = ((const float4*)atom_b)[lane];
        for (int k = 0; k < 256; ++k) {
            float a = atom_embed[(size_t)r * 256 + k];
            float4 w4 = ((const float4*)atom_W)[(size_t)k * 64 + lane];
            acc.x = fmaf(a, w4.x, acc.x);
            acc.y = fmaf(a, w4.y, acc.y);
            acc.z = fmaf(a, w4.z, acc.z);
            acc.w = fmaf(a, w4.w, acc.w);
        }
        ((float4*)E0)[(size_t)r * 64 + lane] = acc;
    }
    // histogram
    if (gidx < N_EDGES) {
        atomicAdd(&dout[ei[gidx]], 1);
        atomicAdd(&din[ei[N_EDGES + gidx]], 1);
    }
}

// norm + h0 (pre-scaled by ns). Grid: 2500 x 256 (wave per node).
__global__ __launch_bounds__(256) void k_nh(
    const int* __restrict__ types, const float* __restrict__ E0,
    const int* __restrict__ dout, const int* __restrict__ din,
    float* __restrict__ ns, float* __restrict__ nd, float* __restrict__ h)
{
    int node = blockIdx.x * 4 + (threadIdx.x >> 6);
    int lane = threadIdx.x & 63;
    if (node >= N_NODES) return;
    int o  = dout[node];
    int in = din[node];
    float nsv = (o  > 0) ? (1.0f / sqrtf((float)o))  : 0.f;
    float ndv = (in > 0) ? (1.0f / sqrtf((float)in)) : 0.f;
    if (lane == 0) { ns[node] = nsv; nd[node] = ndv; }
    int t = types[node];
    float4 v = ((const float4*)E0)[(size_t)t * 64 + lane];
    v.x *= nsv; v.y *= nsv; v.z *= nsv; v.w *= nsv;
    ((float4*)h)[(size_t)node * 64 + lane] = v;
}

__global__ __launch_bounds__(1024) void k_scan(const int* __restrict__ deg,
                                               int* __restrict__ off, int n)
{
    __shared__ int part[1024];
    int t = threadIdx.x;
    int chunk = (n + 1023) / 1024;
    int base = t * chunk;
    int s = 0;
    for (int i = 0; i < chunk; ++i) {
        int idx = base + i;
        if (idx < n) s += deg[idx];
    }
    part[t] = s;
    __syncthreads();
    for (int d = 1; d < 1024; d <<= 1) {
        int v = (t >= d) ? part[t - d] : 0;
        __syncthreads();
        part[t] += v;
        __syncthreads();
    }
    int run = (t == 0) ? 0 : part[t - 1];
    if (t == 0) off[0] = 0;
    for (int i = 0; i < chunk; ++i) {
        int idx = base + i;
        if (idx < n) { run += deg[idx]; off[idx + 1] = run; }
    }
}

__global__ void k_fill(const int* __restrict__ ei, const int* __restrict__ off,
                       int* __restrict__ cur, int* __restrict__ csr)
{
    int e = blockIdx.x * blockDim.x + threadIdx.x;
    if (e >= N_EDGES) return;
    int d = ei[N_EDGES + e];
    int p = off[d] + atomicAdd(&cur[d], 1);
    csr[p] = ei[e];
}

// ---------------------------------------------------------------------------
// Persistent column-chunked aggregation (XCD-local h stripes), unroll-8,
// split-bf16 out. Grid: 2048 x 256. [verified R10]
// ---------------------------------------------------------------------------
__global__ __launch_bounds__(256) void k_agg(
    const float* __restrict__ h, const float* __restrict__ nd,
    const int* __restrict__ off, const int* __restrict__ csr,
    unsigned short* __restrict__ Ah, unsigned short* __restrict__ Al)
{
    int bid  = blockIdx.x;
    int slot = bid & 7;
    int c    = slot >> 1;
    int p    = ((bid >> 3) << 1) | (slot & 1);
    int wave = threadIdx.x >> 6;
    int lane = threadIdx.x & 63;
    int wi   = p * 4 + wave;
    int col  = c * 64 + lane;

    for (int node = wi; node < N_NODES; node += 2048) {
        int s0 = off[node], s1 = off[node + 1];
        float a0 = 0.f, a1 = 0.f, a2 = 0.f, a3 = 0.f;
        float a4 = 0.f, a5 = 0.f, a6 = 0.f, a7 = 0.f;
        int e = s0;
        for (; e + 8 <= s1; e += 8) {
            int i0 = csr[e],     i1 = csr[e + 1], i2 = csr[e + 2], i3 = csr[e + 3];
            int i4 = csr[e + 4], i5 = csr[e + 5], i6 = csr[e + 6], i7 = csr[e + 7];
            float v0 = h[(size_t)i0 * 256 + col];
            float v1 = h[(size_t)i1 * 256 + col];
            float v2 = h[(size_t)i2 * 256 + col];
            float v3 = h[(size_t)i3 * 256 + col];
            float v4 = h[(size_t)i4 * 256 + col];
            float v5 = h[(size_t)i5 * 256 + col];
            float v6 = h[(size_t)i6 * 256 + col];
            float v7 = h[(size_t)i7 * 256 + col];
            a0 += v0; a1 += v1; a2 += v2; a3 += v3;
            a4 += v4; a5 += v5; a6 += v6; a7 += v7;
        }
        for (; e < s1; ++e)
            a0 += h[(size_t)csr[e] * 256 + col];
        float s = (((a0 + a1) + (a2 + a3)) + ((a4 + a5) + (a6 + a7))) * nd[node];
        unsigned short hi, lo;
        split_bf16(s, hi, lo);
        Ah[(size_t)node * 256 + col] = hi;
        Al[(size_t)node * 256 + col] = lo;
    }
}

// conv GEMM: 628 blocks x 256 thr, 4 tiles/block. Tile t=b*4+w: x=t>>3, y=t&7.
// isLast: write split-bf16 (feeds pq), no ns scale.
__global__ __launch_bounds__(256) void k_conv(
    const unsigned short* __restrict__ Ah, const unsigned short* __restrict__ Al,
    const unsigned short* __restrict__ Wh, const unsigned short* __restrict__ Wl,
    const float* __restrict__ bias, const float* __restrict__ scale,
    float* __restrict__ outF, unsigned short* __restrict__ outH,
    unsigned short* __restrict__ outL, int M, int isLast)
{
    int t = blockIdx.x * 4 + (threadIdx.x >> 6);
    int x = t >> 3, y = t & 7;
    if (x * 32 >= M) return;
    if (isLast)
        mfma_tile(Ah, Al, Wh, Wl, bias, nullptr, nullptr, outH, outL,
                  M, x * 32, y * 32, 1);
    else
        mfma_tile(Ah, Al, Wh, Wl, bias, scale, outF, nullptr, nullptr,
                  M, x * 32, y * 32, 1);
}

// pq GEMM: 1252 blocks x 256 thr. Tile t=b*4+w: x=t>>4, r=t&15, half=r>>3, y=r&7.
__global__ __launch_bounds__(256) void k_pq(
    const unsigned short* __restrict__ Ah, const unsigned short* __restrict__ Al,
    const unsigned short* __restrict__ WTh, const unsigned short* __restrict__ WTl,
    float* __restrict__ P, float* __restrict__ Q, int M)
{
    int t = blockIdx.x * 4 + (threadIdx.x >> 6);
    if (t >= 313 * 16) return;
    int x = t >> 4, r = t & 15;
    int half = r >> 3, y = r & 7;
    if (x * 32 >= M) return;
    const unsigned short* wh = WTh + (size_t)(3 + half) * 65536;
    const unsigned short* wl = WTl + (size_t)(3 + half) * 65536;
    mfma_tile(Ah, Al, wh, wl, nullptr, nullptr,
              half ? Q : P, nullptr, nullptr, M, x * 32, y * 32, 0);
}

// ---------------------------------------------------------------------------
// Scoring: 8 chunks x 32 cols, chunk = bid&7 -> XCD-local stripes. [verified]
// ---------------------------------------------------------------------------
__global__ __launch_bounds__(256) void k_score_part(
    const int* __restrict__ cand, const float* __restrict__ P,
    const float* __restrict__ Q, const float* __restrict__ b1,
    const float* __restrict__ W2, float* __restrict__ part)
{
    int bid = blockIdx.x;
    int c   = bid & 7;
    int grp = bid >> 3;
    int cd  = grp * 256 + threadIdx.x;
    if (cd >= N_CAND) return;

    int u = cand[2 * cd];
    int v = cand[2 * cd + 1];
    const float4* P4 = (const float4*)P;
    const float4* Q4 = (const float4*)Q;
    const float4* B4 = (const float4*)b1;
    const float4* W4 = (const float4*)W2;
    size_t pb = (size_t)u * 64 + c * 8;
    size_t qb = (size_t)v * 64 + c * 8;

    float4 p[8], q[8];
    #pragma unroll
    for (int i = 0; i < 8; ++i) p[i] = P4[pb + i];
    #pragma unroll
    for (int i = 0; i < 8; ++i) q[i] = Q4[qb + i];

    float acc = 0.f;
    #pragma unroll
    for (int i = 0; i < 8; ++i) {
        float4 b = B4[c * 8 + i];
        float4 w = W4[c * 8 + i];
        acc = fmaf(relu_f(p[i].x + q[i].x + b.x), w.x, acc);
        acc = fmaf(relu_f(p[i].y + q[i].y + b.y), w.y, acc);
        acc = fmaf(relu_f(p[i].z + q[i].z + b.z), w.z, acc);
        acc = fmaf(relu_f(p[i].w + q[i].w + b.w), w.w, acc);
    }
    part[(size_t)c * N_CAND + cd] = acc;
}

__global__ void k_sred(const float* __restrict__ part,
                       const float* __restrict__ b2, float* __restrict__ out)
{
    int i = blockIdx.x * 256 + threadIdx.x;
    if (i >= N_CAND) return;
    float s = b2[0];
    #pragma unroll
    for (int c = 0; c < 8; ++c) s += part[(size_t)c * N_CAND + i];
    out[i] = s;
}

// ---------------------------------------------------------------------------
extern "C" void kernel_launch(void* const* d_in, const int* in_sizes, int n_in,
                              void* d_out, int out_size, void* d_ws, size_t ws_size,
                              hipStream_t stream)
{
    const int*   atom_types = (const int*)d_in[0];
    const int*   edge_index = (const int*)d_in[2];
    const int*   candidates = (const int*)d_in[3];
    const float* atom_embed = (const float*)d_in[4];
    const float* atom_W     = (const float*)d_in[5];
    const float* atom_b     = (const float*)d_in[6];
    const float* conv_W     = (const float*)d_in[10];
    const float* conv_b     = (const float*)d_in[11];
    const float* s_W1       = (const float*)d_in[12];
    const float* s_b1       = (const float*)d_in[13];
    const float* s_W2       = (const float*)d_in[14];
    const float* s_b2       = (const float*)d_in[15];
    float* out = (float*)d_out;

    char* w = (char*)d_ws;
    size_t o = 0;
    auto alloc = [&](size_t bytes) {
        void* p = w + o;
        o += (bytes + 255) & ~(size_t)255;
        return p;
    };
    int*            ints = (int*)alloc((size_t)3 * N_NODES * 4);   // dego|degi|cur
    float*          h0   = (float*)alloc((size_t)N_NODES * HID * 4);
    float*          h1   = (float*)alloc((size_t)N_NODES * HID * 4);
    float*          Pm   = (float*)alloc((size_t)N_NODES * HID * 4);
    float*          Qm   = (float*)alloc((size_t)N_NODES * HID * 4);
    unsigned short* Ah   = (unsigned short*)alloc((size_t)N_NODES * HID * 2);
    unsigned short* Al   = (unsigned short*)alloc((size_t)N_NODES * HID * 2);
    unsigned short* Ah2  = (unsigned short*)alloc((size_t)N_NODES * HID * 2);
    unsigned short* Al2  = (unsigned short*)alloc((size_t)N_NODES * HID * 2);
    unsigned short* WTh  = (unsigned short*)alloc((size_t)5 * 65536 * 2);
    unsigned short* WTl  = (unsigned short*)alloc((size_t)5 * 65536 * 2);
    float*          E0   = (float*)alloc((size_t)N_ATYPE * HID * 4);
    float*          part = (float*)alloc((size_t)8 * N_CAND * 4);
    float*          ns   = (float*)alloc((size_t)N_NODES * 4);
    float*          nd   = (float*)alloc((size_t)N_NODES * 4);
    int*            off  = (int*)alloc((size_t)(N_NODES + 1) * 4);
    int*            csr  = (int*)alloc((size_t)N_EDGES * 4);
    int* dego = ints;
    int* degi = ints + N_NODES;
    int* cur  = ints + 2 * N_NODES;

    hipMemsetAsync(ints, 0, (size_t)3 * N_NODES * 4, stream);

    // prep_w + E0 + histogram (fused, independent)
    k_pre<<<1280, 256, 0, stream>>>(conv_W, s_W1, atom_embed, atom_W, atom_b,
                                    edge_index, WTh, WTl, E0, dego, degi);
    // norms + h0
    k_nh<<<2500, 256, 0, stream>>>(atom_types, E0, dego, degi, ns, nd, h0);
    k_scan<<<1, 1024, 0, stream>>>(degi, off, N_NODES);
    k_fill<<<(N_EDGES + 255) / 256, 256, 0, stream>>>(edge_index, off, cur, csr);

    const float* hc = h0;
    float* hn = h1;
    for (int L = 0; L < N_MP; ++L) {
        k_agg<<<2048, 256, 0, stream>>>(hc, nd, off, csr, Ah, Al);
        int isLast = (L == N_MP - 1);
        k_conv<<<628, 256, 0, stream>>>(
            Ah, Al, WTh + (size_t)L * 65536, WTl + (size_t)L * 65536,
            conv_b + (size_t)L * HID, ns, hn, Ah2, Al2, N_NODES, isLast);
        float* t = (float*)hc; hc = hn; hn = t;
    }
    // P/Q projection from split-bf16 final h (Ah2/Al2)
    k_pq<<<1252, 256, 0, stream>>>(Ah2, Al2, WTh, WTl, Pm, Qm, N_NODES);

    k_score_part<<<3128, 256, 0, stream>>>(candidates, Pm, Qm, s_b1, s_W2, part);
    k_sred<<<(N_CAND + 255) / 256, 256, 0, stream>>>(part, s_b2, out);
}